// Round 25
// baseline (1066.191 us; speedup 1.0000x reference)
//
#include <hip/hip_runtime.h>

using u16 = unsigned short;
using u32 = unsigned int;

typedef __bf16 bf16x8 __attribute__((ext_vector_type(8)));
typedef float f32x4 __attribute__((ext_vector_type(4)));

typedef __attribute__((address_space(3))) u32 as3_u32;
typedef __attribute__((address_space(1))) const u32 as1_u32;

__device__ __forceinline__ u16 f2bf(float f) {
  u32 u = __builtin_bit_cast(u32, f);
  u = u + 0x7FFFu + ((u >> 16) & 1u);  // round-to-nearest-even
  return (u16)(u >> 16);
}
__device__ __forceinline__ float bf2f(u16 h) {
  return __builtin_bit_cast(float, (u32)h << 16);
}

// async global->LDS, 16B per lane; LDS dest = wave-uniform base + lane*16
__device__ __forceinline__ void gload16(const u16* g, u16* l) {
  __builtin_amdgcn_global_load_lds((as1_u32*)g, (as3_u32*)l, 16, 0, 0);
}

// ------------------------------------------------------------------
// All-weights transpose + f32->bf16, single dispatch, 2 tiles/block.
// Pad 67 (bank-conflict-free, verified r19).
// ------------------------------------------------------------------
__global__ __launch_bounds__(256) void transpose_all(
    const float* __restrict__ w0, u16* __restrict__ o0,   // Wqkv 512x1536
    const float* __restrict__ w1, u16* __restrict__ o1,   // Wout 512x512
    const float* __restrict__ w2, u16* __restrict__ o2,   // W1   512x2048
    const float* __restrict__ w3, u16* __restrict__ o3) { // W2  2048x512
  __shared__ u16 tile[2][64][67];
  int id = blockIdx.x;
  const int layer = id / 384;
  int r = id % 384;
  const float* in;
  u16* out;
  int R, C, bx;
  if (r < 96)        { in = w0; out = o0; R = 512;  C = 1536; bx = 24; }
  else if (r < 128)  { r -= 96;  in = w1; out = o1; R = 512;  C = 512;  bx = 8;  }
  else if (r < 256)  { r -= 128; in = w2; out = o2; R = 512;  C = 2048; bx = 32; }
  else               { r -= 256; in = w3; out = o3; R = 2048; C = 512;  bx = 8;  }
  const long zofs = (long)layer * R * C;
  const int tid = threadIdx.x;
  int c0[2], r0[2];
#pragma unroll
  for (int p = 0; p < 2; ++p) {
    int t = r * 2 + p;
    c0[p] = (t % bx) * 64;
    r0[p] = (t / bx) * 64;
  }

#pragma unroll
  for (int k = 0; k < 4; ++k) {
    int it = tid + k * 256;
    int row = it >> 4, c4 = (it & 15) * 4;
#pragma unroll
    for (int p = 0; p < 2; ++p) {
      float4 v = *reinterpret_cast<const float4*>(
          in + zofs + (long)(r0[p] + row) * C + c0[p] + c4);
      tile[p][row][c4 + 0] = f2bf(v.x);
      tile[p][row][c4 + 1] = f2bf(v.y);
      tile[p][row][c4 + 2] = f2bf(v.z);
      tile[p][row][c4 + 3] = f2bf(v.w);
    }
  }
  __syncthreads();

#pragma unroll
  for (int k = 0; k < 2; ++k) {
    int it = tid + k * 256;
    int cc = it >> 3, r8 = (it & 7) * 8;
#pragma unroll
    for (int p = 0; p < 2; ++p) {
      u16 tmp[8];
#pragma unroll
      for (int e = 0; e < 8; ++e) tmp[e] = tile[p][r8 + e][cc];
      *reinterpret_cast<uint4*>(out + zofs + (long)(c0[p] + cc) * R + r0[p] + r8) =
          *reinterpret_cast<const uint4*>(tmp);
    }
  }
}

// ------------------------------------------------------------------
// General bf16 GEMM, B transposed. 2-phase prefetch (dbuf LDS), BK=64,
// 4 waves, MI x NI frags of mfma 16x16x32. gload_lds w16 + XOR swizzle.
// VT=1: blocks with n0>=1024 also emit vT[n-1024][m] via LDS transpose.
// fp32 output path: PLAIN STORE into per-K-chunk partial buffer.
// ------------------------------------------------------------------
template <int MI, int NI, int VT>
__global__ __launch_bounds__(256) void gemm_bt(
    const u16* __restrict__ A, int lda,
    const u16* __restrict__ B, int ldb,
    const float* __restrict__ bias,
    u16* __restrict__ outBf, int ldob,
    float* __restrict__ outF, int ldof, long ofBatch,
    u16* __restrict__ vtOut,
    int M, int N, int K, int kChunks, float scale, int relu) {
  __shared__ u16 As[2][MI * 32 * 64];
  __shared__ u16 Bs[2][NI * 32 * 64];
  __shared__ u16 Ts[VT ? NI * 32 : 1][72];
  const int m0 = blockIdx.y * (MI * 32), n0 = blockIdx.x * (NI * 32);
  const int tid = threadIdx.x, lane = tid & 63, wid = tid >> 6;
  const int wr = (wid >> 1) * (MI * 16), wc = (wid & 1) * (NI * 16);
  const int r16 = lane & 15, kg = lane >> 4;

  const int lrow = lane >> 3;
  const int lchunk = (lane & 7) ^ lrow;

  f32x4 acc[MI][NI];
#pragma unroll
  for (int i = 0; i < MI; ++i)
#pragma unroll
    for (int j = 0; j < NI; ++j) acc[i][j] = f32x4{0.f, 0.f, 0.f, 0.f};

  const int kcs = K / kChunks;
  const int kbase = kcs * blockIdx.z;
  const int nkt = kcs / 64;

  auto STAGE = [&](int b, int k0) {
#pragma unroll
    for (int i = 0; i < MI; ++i) {
      const int r = i * 32 + wid * 8 + lrow;
      gload16(A + (long)(m0 + r) * lda + k0 + lchunk * 8,
              &As[b][wid * 512 + i * 2048]);
    }
#pragma unroll
    for (int j = 0; j < NI; ++j) {
      const int r = j * 32 + wid * 8 + lrow;
      gload16(B + (long)(n0 + r) * ldb + k0 + lchunk * 8,
              &Bs[b][wid * 512 + j * 2048]);
    }
  };

  STAGE(0, kbase);
  __syncthreads();

  for (int kt = 0; kt < nkt; ++kt) {
    const int cur = kt & 1;
    if (kt + 1 < nkt) STAGE(cur ^ 1, kbase + (kt + 1) * 64);

#pragma unroll
    for (int s = 0; s < 2; ++s) {
      bf16x8 af[MI], bfv[NI];
#pragma unroll
      for (int i = 0; i < MI; ++i) {
        const int r = wr + i * 16 + r16;
        af[i] = *reinterpret_cast<const bf16x8*>(
            &As[cur][r * 64 + (((s * 4 + kg) ^ (r & 7)) << 3)]);
      }
#pragma unroll
      for (int j = 0; j < NI; ++j) {
        const int r = wc + j * 16 + r16;
        bfv[j] = *reinterpret_cast<const bf16x8*>(
            &Bs[cur][r * 64 + (((s * 4 + kg) ^ (r & 7)) << 3)]);
      }
      __builtin_amdgcn_s_setprio(1);
#pragma unroll
      for (int i = 0; i < MI; ++i)
#pragma unroll
        for (int j = 0; j < NI; ++j)
          acc[i][j] = __builtin_amdgcn_mfma_f32_16x16x32_bf16(af[i], bfv[j], acc[i][j], 0, 0, 0);
      __builtin_amdgcn_s_setprio(0);
    }
    __syncthreads();
  }

  const int rg = (lane >> 4) * 4;
  const bool doVT = VT && (n0 >= 1024);
#pragma unroll
  for (int i = 0; i < MI; ++i) {
#pragma unroll
    for (int j = 0; j < NI; ++j) {
      int col = n0 + wc + j * 16 + r16;
      float bv = (bias && blockIdx.z == 0) ? bias[col] : 0.f;
#pragma unroll
      for (int r = 0; r < 4; ++r) {
        int row = m0 + wr + i * 16 + rg + r;
        float v = acc[i][j][r] * scale + bv;
        if (outF)
          outF[(long)blockIdx.z * ofBatch + (long)row * ldof + col] = v;
        if (outBf) {
          if (relu && v < 0.f) v = 0.f;
          u16 hv = f2bf(v);
          outBf[(long)row * ldob + col] = hv;
          if (doVT) Ts[wc + j * 16 + r16][wr + i * 16 + rg + r] = hv;
        }
      }
    }
  }

  if constexpr (VT) {
    if (doVT) {
      __syncthreads();
      const int d0 = n0 - 1024;
      constexpr int CH = MI * 4;
      constexpr int TOT = NI * 32 * CH;
#pragma unroll
      for (int c = 0; c < TOT / 256; ++c) {
        int idx = tid * (TOT / 256) + c;
        int drow = idx / CH, off = (idx % CH) * 8;
        *reinterpret_cast<uint4*>(vtOut + (long)(d0 + drow) * 2048 + m0 + off) =
            *reinterpret_cast<const uint4*>(&Ts[drow][off]);
      }
    }
  }
}

// ------------------------------------------------------------------
// Flash attention, 8-wave blocks (128 q-rows), no-max softmax.
// 1D grid, XCD-aware head grouping. K dbuf, V single-buffered.
// ------------------------------------------------------------------
constexpr int AFP = 72;

__global__ __launch_bounds__(512, 2) void flash_attn_split(
    const u16* __restrict__ qkv, const u16* __restrict__ vT,
    u16* __restrict__ oPart, float* __restrict__ lPart) {
  __shared__ u16 Ks[2][64 * AFP];
  __shared__ u16 Vs[64 * AFP];
  __shared__ u16 Ps[8][16 * AFP];
  const int bid = blockIdx.x;
  const int h = bid & 7;
  const int q0 = ((bid >> 3) & 15) * 128;
  const int split = bid >> 7;
  const int tid = threadIdx.x;
  const int lane = tid & 63, wid = tid >> 6;
  const int r16 = lane & 15, kg8 = (lane >> 4) * 8;

  bf16x8 qa0, qa1;
  {
    union U { uint4 v; u16 hh[8]; } a, b;
    const u16* qrow = qkv + (long)(q0 + wid * 16 + r16) * 1536 + 64 * h;
    a.v = *reinterpret_cast<const uint4*>(qrow + kg8);
    b.v = *reinterpret_cast<const uint4*>(qrow + 32 + kg8);
#pragma unroll
    for (int i = 0; i < 8; ++i) {
      a.hh[i] = f2bf(bf2f(a.hh[i]) * 0.125f);
      b.hh[i] = f2bf(bf2f(b.hh[i]) * 0.125f);
    }
    qa0 = __builtin_bit_cast(bf16x8, a.v);
    qa1 = __builtin_bit_cast(bf16x8, b.v);
  }

  const int srow = tid >> 3;
  const int scol = (tid & 7) * 8;
  const u16* kgl = qkv + 512 + 64 * h + scol;
  const u16* vgl = vT + (long)(64 * h + srow) * 2048 + scol;

  uint4 kr0, vr0;
  auto LOAD = [&](int g) {
    kr0 = *reinterpret_cast<const uint4*>(kgl + (long)(g * 64 + srow) * 1536);
    vr0 = *reinterpret_cast<const uint4*>(vgl + g * 64);
  };
  auto STOREK = [&](int b) {
    *reinterpret_cast<uint4*>(&Ks[b][srow * AFP + scol]) = kr0;
  };
  auto STOREV = [&]() {
    *reinterpret_cast<uint4*>(&Vs[srow * AFP + scol]) = vr0;
  };

  f32x4 oacc[4];
#pragma unroll
  for (int j = 0; j < 4; ++j) oacc[j] = f32x4{0.f, 0.f, 0.f, 0.f};
  float lsum[4] = {0.f, 0.f, 0.f, 0.f};

  const int g0 = split * 8;
  LOAD(g0);
  STOREK(0);
  STOREV();
  __syncthreads();

  for (int t = 0; t < 8; ++t) {
    const int cur = t & 1;
    if (t < 7) LOAD(g0 + t + 1);

    f32x4 sacc[4];
#pragma unroll
    for (int j = 0; j < 4; ++j) sacc[j] = f32x4{0.f, 0.f, 0.f, 0.f};
    __builtin_amdgcn_s_setprio(1);
#pragma unroll
    for (int j = 0; j < 4; ++j) {
      bf16x8 b0 = *reinterpret_cast<const bf16x8*>(&Ks[cur][(j * 16 + r16) * AFP + kg8]);
      bf16x8 b1 = *reinterpret_cast<const bf16x8*>(&Ks[cur][(j * 16 + r16) * AFP + 32 + kg8]);
      sacc[j] = __builtin_amdgcn_mfma_f32_16x16x32_bf16(qa0, b0, sacc[j], 0, 0, 0);
      sacc[j] = __builtin_amdgcn_mfma_f32_16x16x32_bf16(qa1, b1, sacc[j], 0, 0, 0);
    }
    __builtin_amdgcn_s_setprio(0);

#pragma unroll
    for (int r = 0; r < 4; ++r) {
      float e0 = __expf(sacc[0][r]);
      float e1 = __expf(sacc[1][r]);
      float e2 = __expf(sacc[2][r]);
      float e3 = __expf(sacc[3][r]);
      lsum[r] += (e0 + e1) + (e2 + e3);
      int prow = (lane >> 4) * 4 + r;
      Ps[wid][prow * AFP + r16] = f2bf(e0);
      Ps[wid][prow * AFP + 16 + r16] = f2bf(e1);
      Ps[wid][prow * AFP + 32 + r16] = f2bf(e2);
      Ps[wid][prow * AFP + 48 + r16] = f2bf(e3);
    }

#pragma unroll
    for (int st = 0; st < 2; ++st) {
      bf16x8 pa = *reinterpret_cast<const bf16x8*>(&Ps[wid][r16 * AFP + st * 32 + kg8]);
      __builtin_amdgcn_s_setprio(1);
#pragma unroll
      for (int j = 0; j < 4; ++j) {
        bf16x8 bv = *reinterpret_cast<const bf16x8*>(&Vs[(j * 16 + r16) * AFP + st * 32 + kg8]);
        oacc[j] = __builtin_amdgcn_mfma_f32_16x16x32_bf16(pa, bv, oacc[j], 0, 0, 0);
      }
      __builtin_amdgcn_s_setprio(0);
    }

    if (t < 7) {
      STOREK(cur ^ 1);
      __syncthreads();
      STOREV();
      __syncthreads();
    }
  }

  const int rg = (lane >> 4) * 4;
#pragma unroll
  for (int r = 0; r < 4; ++r) {
    float ls = lsum[r];
#pragma unroll
    for (int o = 1; o < 16; o <<= 1) ls += __shfl_xor(ls, o);
    int row = q0 + wid * 16 + rg + r;
    if (r16 == 0) lPart[(long)(split * 8 + h) * 2048 + row] = ls;
#pragma unroll
    for (int j = 0; j < 4; ++j)
      oPart[(long)split * 2048 * 512 + (long)row * 512 + 64 * h + j * 16 + r16] =
          f2bf(oacc[j][r]);
  }
}

// ------------------------------------------------------------------
// Fused: combine KV-split bf16 partials -> attn bf16, AND x += fsmn(v).
// FSMN reads V from vT[d][t] (row-local 11-tap window, 22 contiguous
// bytes per column) instead of qkv columns (12 x 3KB-stride scalars).
// Values bit-identical (vT is an exact copy of V).
// ------------------------------------------------------------------
__global__ __launch_bounds__(256) void attn_norm_fsmn(
    const u16* __restrict__ oPart, const float* __restrict__ lPart,
    u16* __restrict__ attn, float* __restrict__ x,
    const u16* __restrict__ vT, const float* __restrict__ fw) {
  const int t = blockIdx.x;
  const int d = threadIdx.x * 2;
  const int h = d >> 6;
  float l = 0.f;
#pragma unroll
  for (int s = 0; s < 4; ++s) l += lPart[(long)(s * 8 + h) * 2048 + t];
  float ox = 0.f, oy = 0.f;
#pragma unroll
  for (int s = 0; s < 4; ++s) {
    const u32 v = *reinterpret_cast<const u32*>(
        oPart + (long)s * 2048 * 512 + (long)t * 512 + d);
    ox += bf2f((u16)v);
    oy += bf2f((u16)(v >> 16));
  }
  const float inv = 1.f / l;
  u16* out = attn + (long)t * 512 + d;
  out[0] = f2bf(ox * inv);
  out[1] = f2bf(oy * inv);

  const u16* v0 = vT + (long)d * 2048;        // row d of V^T
  const u16* v1 = vT + (long)(d + 1) * 2048;  // row d+1
  float s0 = bf2f(v0[t]);
  float s1 = bf2f(v1[t]);
#pragma unroll
  for (int j = 0; j < 11; ++j) {
    int ts = t + j - 5;
    if (ts >= 0 && ts < 2048) {
      s0 += fw[d * 11 + j] * bf2f(v0[ts]);
      s1 += fw[(d + 1) * 11 + j] * bf2f(v1[ts]);
    }
  }
  x[(long)t * 512 + d] += s0;
  x[(long)t * 512 + d + 1] += s1;
}

// ------------------------------------------------------------------
// LayerNorm with fused split-K reduction: x += sum of NACC partial
// buffers, write x back, then LN(x) -> out. Wave-per-row, no barriers.
// ------------------------------------------------------------------
template <int OUTBF, int NACC>
__global__ __launch_bounds__(256) void ln_accum(
    float* __restrict__ x, const float* __restrict__ part,
    const float* __restrict__ g, const float* __restrict__ bta,
    void* __restrict__ out) {
  const int lane = threadIdx.x & 63;
  const int row = blockIdx.x * 4 + (threadIdx.x >> 6);
  float* xr = x + (long)row * 512 + lane * 8;
  float4 v0 = *reinterpret_cast<const float4*>(xr);
  float4 v1 = *reinterpret_cast<const float4*>(xr + 4);
#pragma unroll
  for (int a = 0; a < NACC; ++a) {
    const float* pr = part + (long)a * 2048 * 512 + (long)row * 512 + lane * 8;
    const float4 p0 = *reinterpret_cast<const float4*>(pr);
    const float4 p1 = *reinterpret_cast<const float4*>(pr + 4);
    v0.x += p0.x; v0.y += p0.y; v0.z += p0.z; v0.w += p0.w;
    v1.x += p1.x; v1.y += p1.y; v1.z += p1.z; v1.w += p1.w;
  }
  if (NACC) {
    *reinterpret_cast<float4*>(xr) = v0;
    *reinterpret_cast<float4*>(xr + 4) = v1;
  }
  float s = ((v0.x + v0.y) + (v0.z + v0.w)) + ((v1.x + v1.y) + (v1.z + v1.w));
  float ss = ((v0.x * v0.x + v0.y * v0.y) + (v0.z * v0.z + v0.w * v0.w)) +
             ((v1.x * v1.x + v1.y * v1.y) + (v1.z * v1.z + v1.w * v1.w));
#pragma unroll
  for (int o = 32; o; o >>= 1) {
    s += __shfl_xor(s, o);
    ss += __shfl_xor(ss, o);
  }
  const float mean = s * (1.f / 512.f);
  const float var = ss * (1.f / 512.f) - mean * mean;
  const float inv = rsqrtf(var + 1e-5f);
  const float4 g0 = *reinterpret_cast<const float4*>(g + lane * 8);
  const float4 g1 = *reinterpret_cast<const float4*>(g + lane * 8 + 4);
  const float4 b0 = *reinterpret_cast<const float4*>(bta + lane * 8);
  const float4 b1 = *reinterpret_cast<const float4*>(bta + lane * 8 + 4);
  float y[8];
  y[0] = (v0.x - mean) * inv * g0.x + b0.x;
  y[1] = (v0.y - mean) * inv * g0.y + b0.y;
  y[2] = (v0.z - mean) * inv * g0.z + b0.z;
  y[3] = (v0.w - mean) * inv * g0.w + b0.w;
  y[4] = (v1.x - mean) * inv * g1.x + b1.x;
  y[5] = (v1.y - mean) * inv * g1.y + b1.y;
  y[6] = (v1.z - mean) * inv * g1.z + b1.z;
  y[7] = (v1.w - mean) * inv * g1.w + b1.w;
  if (OUTBF) {
    u16 tmp[8];
#pragma unroll
    for (int e = 0; e < 8; ++e) tmp[e] = f2bf(y[e]);
    *reinterpret_cast<uint4*>((u16*)out + (long)row * 512 + lane * 8) =
        *reinterpret_cast<const uint4*>(tmp);
  } else {
    float* o = (float*)out + (long)row * 512 + lane * 8;
    *reinterpret_cast<float4*>(o) = make_float4(y[0], y[1], y[2], y[3]);
    *reinterpret_cast<float4*>(o + 4) = make_float4(y[4], y[5], y[6], y[7]);
  }
}

// ------------------------------------------------------------------

extern "C" void kernel_launch(void* const* d_in, const int* in_sizes, int n_in,
                              void* d_out, int out_size, void* d_ws, size_t ws_size,
                              hipStream_t stream) {
  const float* in_x = (const float*)d_in[0];
  const float* ln1_g = (const float*)d_in[1];
  const float* ln1_b = (const float*)d_in[2];
  const float* Wqkv = (const float*)d_in[3];
  const float* bqkv = (const float*)d_in[4];
  const float* fsmn_w = (const float*)d_in[5];
  const float* Wout = (const float*)d_in[6];
  const float* bout = (const float*)d_in[7];
  const float* ln2_g = (const float*)d_in[8];
  const float* ln2_b = (const float*)d_in[9];
  const float* W1 = (const float*)d_in[10];
  const float* b1 = (const float*)d_in[11];
  const float* W2 = (const float*)d_in[12];
  const float* b2 = (const float*)d_in[13];
  const float* after_g = (const float*)d_in[14];
  const float* after_b = (const float*)d_in[15];

  const int T = 2048, D = 512, F = 2048, L = 8;

  char* p = (char*)d_ws;
  auto alloc = [&](size_t bytes) {
    char* r = p;
    p += (bytes + 255) & ~size_t(255);
    return r;
  };
  u16* WqkvT = (u16*)alloc(8L * 1536 * 512 * 2);
  u16* WoutT = (u16*)alloc(8L * 512 * 512 * 2);
  u16* W1T = (u16*)alloc(8L * 2048 * 512 * 2);
  u16* W2T = (u16*)alloc(8L * 512 * 2048 * 2);
  float* x = (float*)alloc((long)T * D * 4);
  u16* x1 = (u16*)alloc((long)T * D * 2);
  u16* qkv = (u16*)alloc((long)T * 1536 * 2);
  u16* vT = (u16*)alloc((long)D * T * 2);
  u16* attn = (u16*)alloc((long)T * D * 2);
  u16* hb = (u16*)alloc((long)T * F * 2);
  u16* oPart = (u16*)alloc(4L * T * D * 2);
  float* lPart = (float*)alloc(4L * 8 * T * 4);
  float* wPart = (float*)alloc(2L * T * D * 4);

  // ---- pre-pass: residual stream + bf16 transposed weights (1 dispatch) ----
  hipMemcpyAsync(x, in_x, (long)T * D * 4, hipMemcpyDeviceToDevice, stream);
  transpose_all<<<dim3(384 * 8, 1, 1), 256, 0, stream>>>(
      Wqkv, WqkvT, Wout, WoutT, W1, W1T, W2, W2T);

  const long OFB = (long)2048 * 512;
  for (int l = 0; l < L; ++l) {
    if (l == 0)
      ln_accum<1, 0><<<T / 4, 256, 0, stream>>>(x, (const float*)nullptr,
                                                ln1_g + 512 * l, ln1_b + 512 * l, x1);
    else
      ln_accum<1, 2><<<T / 4, 256, 0, stream>>>(x, wPart,
                                                ln1_g + 512 * l, ln1_b + 512 * l, x1);
    // QKV GEMM + fused vT emit
    gemm_bt<2, 2, 1><<<dim3(24, 32, 1), 256, 0, stream>>>(
        x1, 512, WqkvT + (long)l * 1536 * 512, 512, bqkv + 1536 * l,
        qkv, 1536, (float*)nullptr, 0, 0, vT, T, 1536, 512, 1, 1.f, 0);
    // flash attention partials
    flash_attn_split<<<dim3(512, 1, 1), 512, 0, stream>>>(qkv, vT, oPart, lPart);
    // combine partials -> attn, and x += fsmn(v)  (V read from vT)
    attn_norm_fsmn<<<T, 256, 0, stream>>>(oPart, lPart, attn, x, vT,
                                          fsmn_w + (long)l * 512 * 11);
    // wPart[z] = attn @ Wout chunk z (+ bout in z=0)
    gemm_bt<2, 2, 0><<<dim3(8, 32, 2), 256, 0, stream>>>(
        attn, 512, WoutT + (long)l * 512 * 512, 512, bout + 512 * l,
        (u16*)nullptr, 0, wPart, 512, OFB, (u16*)nullptr, T, 512, 512, 2, 1.f, 0);
    // LN2 folds Wout partials
    ln_accum<1, 2><<<T / 4, 256, 0, stream>>>(x, wPart,
                                              ln2_g + 512 * l, ln2_b + 512 * l, x1);
    // hb = relu(x1 @ W1 + b1)
    gemm_bt<2, 2, 0><<<dim3(32, 32, 1), 256, 0, stream>>>(
        x1, 512, W1T + (long)l * 2048 * 512, 512, b1 + 2048 * l,
        hb, 2048, (float*)nullptr, 0, 0, (u16*)nullptr, T, 2048, 512, 1, 1.f, 1);
    // wPart[z] = hb @ W2 chunk z (+ b2 in z=0)
    gemm_bt<2, 2, 0><<<dim3(8, 32, 2), 256, 0, stream>>>(
        hb, 2048, W2T + (long)l * 512 * 2048, 2048, b2 + 512 * l,
        (u16*)nullptr, 0, wPart, 512, OFB, (u16*)nullptr, T, 512, 2048, 2, 1.f, 0);
  }
  // final LN folds layer 7's W2 partials
  ln_accum<0, 2><<<T / 4, 256, 0, stream>>>(x, wPart, after_g, after_b,
                                            (float*)d_out);
}

// Round 26
// 712.206 us; speedup vs baseline: 1.4970x; 1.4970x over previous
//
#include <hip/hip_runtime.h>

using u16 = unsigned short;
using u32 = unsigned int;

typedef __bf16 bf16x8 __attribute__((ext_vector_type(8)));
typedef float f32x4 __attribute__((ext_vector_type(4)));

typedef __attribute__((address_space(3))) u32 as3_u32;
typedef __attribute__((address_space(1))) const u32 as1_u32;

__device__ __forceinline__ u16 f2bf(float f) {
  u32 u = __builtin_bit_cast(u32, f);
  u = u + 0x7FFFu + ((u >> 16) & 1u);  // round-to-nearest-even
  return (u16)(u >> 16);
}
__device__ __forceinline__ float bf2f(u16 h) {
  return __builtin_bit_cast(float, (u32)h << 16);
}

// async global->LDS, 16B per lane; LDS dest = wave-uniform base + lane*16
__device__ __forceinline__ void gload16(const u16* g, u16* l) {
  __builtin_amdgcn_global_load_lds((as1_u32*)g, (as3_u32*)l, 16, 0, 0);
}

// ------------------------------------------------------------------
// All-weights transpose + f32->bf16, single dispatch, 2 tiles/block.
// Pad 67 (bank-conflict-free, verified r19).
// ------------------------------------------------------------------
__global__ __launch_bounds__(256) void transpose_all(
    const float* __restrict__ w0, u16* __restrict__ o0,   // Wqkv 512x1536
    const float* __restrict__ w1, u16* __restrict__ o1,   // Wout 512x512
    const float* __restrict__ w2, u16* __restrict__ o2,   // W1   512x2048
    const float* __restrict__ w3, u16* __restrict__ o3) { // W2  2048x512
  __shared__ u16 tile[2][64][67];
  int id = blockIdx.x;
  const int layer = id / 384;
  int r = id % 384;
  const float* in;
  u16* out;
  int R, C, bx;
  if (r < 96)        { in = w0; out = o0; R = 512;  C = 1536; bx = 24; }
  else if (r < 128)  { r -= 96;  in = w1; out = o1; R = 512;  C = 512;  bx = 8;  }
  else if (r < 256)  { r -= 128; in = w2; out = o2; R = 512;  C = 2048; bx = 32; }
  else               { r -= 256; in = w3; out = o3; R = 2048; C = 512;  bx = 8;  }
  const long zofs = (long)layer * R * C;
  const int tid = threadIdx.x;
  int c0[2], r0[2];
#pragma unroll
  for (int p = 0; p < 2; ++p) {
    int t = r * 2 + p;
    c0[p] = (t % bx) * 64;
    r0[p] = (t / bx) * 64;
  }

#pragma unroll
  for (int k = 0; k < 4; ++k) {
    int it = tid + k * 256;
    int row = it >> 4, c4 = (it & 15) * 4;
#pragma unroll
    for (int p = 0; p < 2; ++p) {
      float4 v = *reinterpret_cast<const float4*>(
          in + zofs + (long)(r0[p] + row) * C + c0[p] + c4);
      tile[p][row][c4 + 0] = f2bf(v.x);
      tile[p][row][c4 + 1] = f2bf(v.y);
      tile[p][row][c4 + 2] = f2bf(v.z);
      tile[p][row][c4 + 3] = f2bf(v.w);
    }
  }
  __syncthreads();

#pragma unroll
  for (int k = 0; k < 2; ++k) {
    int it = tid + k * 256;
    int cc = it >> 3, r8 = (it & 7) * 8;
#pragma unroll
    for (int p = 0; p < 2; ++p) {
      u16 tmp[8];
#pragma unroll
      for (int e = 0; e < 8; ++e) tmp[e] = tile[p][r8 + e][cc];
      *reinterpret_cast<uint4*>(out + zofs + (long)(c0[p] + cc) * R + r0[p] + r8) =
          *reinterpret_cast<const uint4*>(tmp);
    }
  }
}

// ------------------------------------------------------------------
// General bf16 GEMM, B transposed. 2-phase prefetch (dbuf LDS), BK=64,
// 4 waves, MI x NI frags of mfma 16x16x32. gload_lds w16 + XOR swizzle.
// VT=1: blocks with n0>=1024 also emit vT[n-1024][m] via LDS transpose.
// fp32 output path: PLAIN STORE into per-K-chunk partial buffer.
// ------------------------------------------------------------------
template <int MI, int NI, int VT>
__global__ __launch_bounds__(256) void gemm_bt(
    const u16* __restrict__ A, int lda,
    const u16* __restrict__ B, int ldb,
    const float* __restrict__ bias,
    u16* __restrict__ outBf, int ldob,
    float* __restrict__ outF, int ldof, long ofBatch,
    u16* __restrict__ vtOut,
    int M, int N, int K, int kChunks, float scale, int relu) {
  __shared__ u16 As[2][MI * 32 * 64];
  __shared__ u16 Bs[2][NI * 32 * 64];
  __shared__ u16 Ts[VT ? NI * 32 : 1][72];
  const int m0 = blockIdx.y * (MI * 32), n0 = blockIdx.x * (NI * 32);
  const int tid = threadIdx.x, lane = tid & 63, wid = tid >> 6;
  const int wr = (wid >> 1) * (MI * 16), wc = (wid & 1) * (NI * 16);
  const int r16 = lane & 15, kg = lane >> 4;

  const int lrow = lane >> 3;
  const int lchunk = (lane & 7) ^ lrow;

  f32x4 acc[MI][NI];
#pragma unroll
  for (int i = 0; i < MI; ++i)
#pragma unroll
    for (int j = 0; j < NI; ++j) acc[i][j] = f32x4{0.f, 0.f, 0.f, 0.f};

  const int kcs = K / kChunks;
  const int kbase = kcs * blockIdx.z;
  const int nkt = kcs / 64;

  auto STAGE = [&](int b, int k0) {
#pragma unroll
    for (int i = 0; i < MI; ++i) {
      const int r = i * 32 + wid * 8 + lrow;
      gload16(A + (long)(m0 + r) * lda + k0 + lchunk * 8,
              &As[b][wid * 512 + i * 2048]);
    }
#pragma unroll
    for (int j = 0; j < NI; ++j) {
      const int r = j * 32 + wid * 8 + lrow;
      gload16(B + (long)(n0 + r) * ldb + k0 + lchunk * 8,
              &Bs[b][wid * 512 + j * 2048]);
    }
  };

  STAGE(0, kbase);
  __syncthreads();

  for (int kt = 0; kt < nkt; ++kt) {
    const int cur = kt & 1;
    if (kt + 1 < nkt) STAGE(cur ^ 1, kbase + (kt + 1) * 64);

#pragma unroll
    for (int s = 0; s < 2; ++s) {
      bf16x8 af[MI], bfv[NI];
#pragma unroll
      for (int i = 0; i < MI; ++i) {
        const int r = wr + i * 16 + r16;
        af[i] = *reinterpret_cast<const bf16x8*>(
            &As[cur][r * 64 + (((s * 4 + kg) ^ (r & 7)) << 3)]);
      }
#pragma unroll
      for (int j = 0; j < NI; ++j) {
        const int r = wc + j * 16 + r16;
        bfv[j] = *reinterpret_cast<const bf16x8*>(
            &Bs[cur][r * 64 + (((s * 4 + kg) ^ (r & 7)) << 3)]);
      }
      __builtin_amdgcn_s_setprio(1);
#pragma unroll
      for (int i = 0; i < MI; ++i)
#pragma unroll
        for (int j = 0; j < NI; ++j)
          acc[i][j] = __builtin_amdgcn_mfma_f32_16x16x32_bf16(af[i], bfv[j], acc[i][j], 0, 0, 0);
      __builtin_amdgcn_s_setprio(0);
    }
    __syncthreads();
  }

  const int rg = (lane >> 4) * 4;
  const bool doVT = VT && (n0 >= 1024);
#pragma unroll
  for (int i = 0; i < MI; ++i) {
#pragma unroll
    for (int j = 0; j < NI; ++j) {
      int col = n0 + wc + j * 16 + r16;
      float bv = (bias && blockIdx.z == 0) ? bias[col] : 0.f;
#pragma unroll
      for (int r = 0; r < 4; ++r) {
        int row = m0 + wr + i * 16 + rg + r;
        float v = acc[i][j][r] * scale + bv;
        if (outF)
          outF[(long)blockIdx.z * ofBatch + (long)row * ldof + col] = v;
        if (outBf) {
          if (relu && v < 0.f) v = 0.f;
          u16 hv = f2bf(v);
          outBf[(long)row * ldob + col] = hv;
          if (doVT) Ts[wc + j * 16 + r16][wr + i * 16 + rg + r] = hv;
        }
      }
    }
  }

  if constexpr (VT) {
    if (doVT) {
      __syncthreads();
      const int d0 = n0 - 1024;
      constexpr int CH = MI * 4;
      constexpr int TOT = NI * 32 * CH;
#pragma unroll
      for (int c = 0; c < TOT / 256; ++c) {
        int idx = tid * (TOT / 256) + c;
        int drow = idx / CH, off = (idx % CH) * 8;
        *reinterpret_cast<uint4*>(vtOut + (long)(d0 + drow) * 2048 + m0 + off) =
            *reinterpret_cast<const uint4*>(&Ts[drow][off]);
      }
    }
  }
}

// ------------------------------------------------------------------
// Flash attention, 8-wave blocks (128 q-rows), no-max softmax.
// 1D grid, XCD-aware head grouping. K dbuf, V single-buffered.
// ------------------------------------------------------------------
constexpr int AFP = 72;

__global__ __launch_bounds__(512, 2) void flash_attn_split(
    const u16* __restrict__ qkv, const u16* __restrict__ vT,
    u16* __restrict__ oPart, float* __restrict__ lPart) {
  __shared__ u16 Ks[2][64 * AFP];
  __shared__ u16 Vs[64 * AFP];
  __shared__ u16 Ps[8][16 * AFP];
  const int bid = blockIdx.x;
  const int h = bid & 7;
  const int q0 = ((bid >> 3) & 15) * 128;
  const int split = bid >> 7;
  const int tid = threadIdx.x;
  const int lane = tid & 63, wid = tid >> 6;
  const int r16 = lane & 15, kg8 = (lane >> 4) * 8;

  bf16x8 qa0, qa1;
  {
    union U { uint4 v; u16 hh[8]; } a, b;
    const u16* qrow = qkv + (long)(q0 + wid * 16 + r16) * 1536 + 64 * h;
    a.v = *reinterpret_cast<const uint4*>(qrow + kg8);
    b.v = *reinterpret_cast<const uint4*>(qrow + 32 + kg8);
#pragma unroll
    for (int i = 0; i < 8; ++i) {
      a.hh[i] = f2bf(bf2f(a.hh[i]) * 0.125f);
      b.hh[i] = f2bf(bf2f(b.hh[i]) * 0.125f);
    }
    qa0 = __builtin_bit_cast(bf16x8, a.v);
    qa1 = __builtin_bit_cast(bf16x8, b.v);
  }

  const int srow = tid >> 3;
  const int scol = (tid & 7) * 8;
  const u16* kgl = qkv + 512 + 64 * h + scol;
  const u16* vgl = vT + (long)(64 * h + srow) * 2048 + scol;

  uint4 kr0, vr0;
  auto LOAD = [&](int g) {
    kr0 = *reinterpret_cast<const uint4*>(kgl + (long)(g * 64 + srow) * 1536);
    vr0 = *reinterpret_cast<const uint4*>(vgl + g * 64);
  };
  auto STOREK = [&](int b) {
    *reinterpret_cast<uint4*>(&Ks[b][srow * AFP + scol]) = kr0;
  };
  auto STOREV = [&]() {
    *reinterpret_cast<uint4*>(&Vs[srow * AFP + scol]) = vr0;
  };

  f32x4 oacc[4];
#pragma unroll
  for (int j = 0; j < 4; ++j) oacc[j] = f32x4{0.f, 0.f, 0.f, 0.f};
  float lsum[4] = {0.f, 0.f, 0.f, 0.f};

  const int g0 = split * 8;
  LOAD(g0);
  STOREK(0);
  STOREV();
  __syncthreads();

  for (int t = 0; t < 8; ++t) {
    const int cur = t & 1;
    if (t < 7) LOAD(g0 + t + 1);

    f32x4 sacc[4];
#pragma unroll
    for (int j = 0; j < 4; ++j) sacc[j] = f32x4{0.f, 0.f, 0.f, 0.f};
    __builtin_amdgcn_s_setprio(1);
#pragma unroll
    for (int j = 0; j < 4; ++j) {
      bf16x8 b0 = *reinterpret_cast<const bf16x8*>(&Ks[cur][(j * 16 + r16) * AFP + kg8]);
      bf16x8 b1 = *reinterpret_cast<const bf16x8*>(&Ks[cur][(j * 16 + r16) * AFP + 32 + kg8]);
      sacc[j] = __builtin_amdgcn_mfma_f32_16x16x32_bf16(qa0, b0, sacc[j], 0, 0, 0);
      sacc[j] = __builtin_amdgcn_mfma_f32_16x16x32_bf16(qa1, b1, sacc[j], 0, 0, 0);
    }
    __builtin_amdgcn_s_setprio(0);

#pragma unroll
    for (int r = 0; r < 4; ++r) {
      float e0 = __expf(sacc[0][r]);
      float e1 = __expf(sacc[1][r]);
      float e2 = __expf(sacc[2][r]);
      float e3 = __expf(sacc[3][r]);
      lsum[r] += (e0 + e1) + (e2 + e3);
      int prow = (lane >> 4) * 4 + r;
      Ps[wid][prow * AFP + r16] = f2bf(e0);
      Ps[wid][prow * AFP + 16 + r16] = f2bf(e1);
      Ps[wid][prow * AFP + 32 + r16] = f2bf(e2);
      Ps[wid][prow * AFP + 48 + r16] = f2bf(e3);
    }

#pragma unroll
    for (int st = 0; st < 2; ++st) {
      bf16x8 pa = *reinterpret_cast<const bf16x8*>(&Ps[wid][r16 * AFP + st * 32 + kg8]);
      __builtin_amdgcn_s_setprio(1);
#pragma unroll
      for (int j = 0; j < 4; ++j) {
        bf16x8 bv = *reinterpret_cast<const bf16x8*>(&Vs[(j * 16 + r16) * AFP + st * 32 + kg8]);
        oacc[j] = __builtin_amdgcn_mfma_f32_16x16x32_bf16(pa, bv, oacc[j], 0, 0, 0);
      }
      __builtin_amdgcn_s_setprio(0);
    }

    if (t < 7) {
      STOREK(cur ^ 1);
      __syncthreads();
      STOREV();
      __syncthreads();
    }
  }

  const int rg = (lane >> 4) * 4;
#pragma unroll
  for (int r = 0; r < 4; ++r) {
    float ls = lsum[r];
#pragma unroll
    for (int o = 1; o < 16; o <<= 1) ls += __shfl_xor(ls, o);
    int row = q0 + wid * 16 + rg + r;
    if (r16 == 0) lPart[(long)(split * 8 + h) * 2048 + row] = ls;
#pragma unroll
    for (int j = 0; j < 4; ++j)
      oPart[(long)split * 2048 * 512 + (long)row * 512 + 64 * h + j * 16 + r16] =
          f2bf(oacc[j][r]);
  }
}

// ------------------------------------------------------------------
// Fused: combine KV-split bf16 partials -> attn bf16, AND x += fsmn(v).
// V read from qkv columns: adjacent lanes -> adjacent d -> coalesced
// per tap; the 11 row-reads are L2-reused across blocks. (r25's vT
// layout was wave-scattered: 4KB between lanes.)
// ------------------------------------------------------------------
__global__ __launch_bounds__(256) void attn_norm_fsmn(
    const u16* __restrict__ oPart, const float* __restrict__ lPart,
    u16* __restrict__ attn, float* __restrict__ x,
    const u16* __restrict__ qkv, const float* __restrict__ fw) {
  const int t = blockIdx.x;
  const int d = threadIdx.x * 2;
  const int h = d >> 6;
  float l = 0.f;
#pragma unroll
  for (int s = 0; s < 4; ++s) l += lPart[(long)(s * 8 + h) * 2048 + t];
  float ox = 0.f, oy = 0.f;
#pragma unroll
  for (int s = 0; s < 4; ++s) {
    const u32 v = *reinterpret_cast<const u32*>(
        oPart + (long)s * 2048 * 512 + (long)t * 512 + d);
    ox += bf2f((u16)v);
    oy += bf2f((u16)(v >> 16));
  }
  const float inv = 1.f / l;
  u16* out = attn + (long)t * 512 + d;
  out[0] = f2bf(ox * inv);
  out[1] = f2bf(oy * inv);

  const u16* v = qkv + 1024 + d;
  float s0 = bf2f(v[(long)t * 1536]);
  float s1 = bf2f(v[(long)t * 1536 + 1]);
#pragma unroll
  for (int j = 0; j < 11; ++j) {
    int ts = t + j - 5;
    if (ts >= 0 && ts < 2048) {
      float w0 = fw[d * 11 + j], w1 = fw[(d + 1) * 11 + j];
      s0 += w0 * bf2f(v[(long)ts * 1536]);
      s1 += w1 * bf2f(v[(long)ts * 1536 + 1]);
    }
  }
  x[(long)t * 512 + d] += s0;
  x[(long)t * 512 + d + 1] += s1;
}

// ------------------------------------------------------------------
// LayerNorm with fused split-K reduction: x += sum of NACC partial
// buffers, write x back, then LN(x) -> out. Wave-per-row, no barriers.
// ------------------------------------------------------------------
template <int OUTBF, int NACC>
__global__ __launch_bounds__(256) void ln_accum(
    float* __restrict__ x, const float* __restrict__ part,
    const float* __restrict__ g, const float* __restrict__ bta,
    void* __restrict__ out) {
  const int lane = threadIdx.x & 63;
  const int row = blockIdx.x * 4 + (threadIdx.x >> 6);
  float* xr = x + (long)row * 512 + lane * 8;
  float4 v0 = *reinterpret_cast<const float4*>(xr);
  float4 v1 = *reinterpret_cast<const float4*>(xr + 4);
#pragma unroll
  for (int a = 0; a < NACC; ++a) {
    const float* pr = part + (long)a * 2048 * 512 + (long)row * 512 + lane * 8;
    const float4 p0 = *reinterpret_cast<const float4*>(pr);
    const float4 p1 = *reinterpret_cast<const float4*>(pr + 4);
    v0.x += p0.x; v0.y += p0.y; v0.z += p0.z; v0.w += p0.w;
    v1.x += p1.x; v1.y += p1.y; v1.z += p1.z; v1.w += p1.w;
  }
  if (NACC) {
    *reinterpret_cast<float4*>(xr) = v0;
    *reinterpret_cast<float4*>(xr + 4) = v1;
  }
  float s = ((v0.x + v0.y) + (v0.z + v0.w)) + ((v1.x + v1.y) + (v1.z + v1.w));
  float ss = ((v0.x * v0.x + v0.y * v0.y) + (v0.z * v0.z + v0.w * v0.w)) +
             ((v1.x * v1.x + v1.y * v1.y) + (v1.z * v1.z + v1.w * v1.w));
#pragma unroll
  for (int o = 32; o; o >>= 1) {
    s += __shfl_xor(s, o);
    ss += __shfl_xor(ss, o);
  }
  const float mean = s * (1.f / 512.f);
  const float var = ss * (1.f / 512.f) - mean * mean;
  const float inv = rsqrtf(var + 1e-5f);
  const float4 g0 = *reinterpret_cast<const float4*>(g + lane * 8);
  const float4 g1 = *reinterpret_cast<const float4*>(g + lane * 8 + 4);
  const float4 b0 = *reinterpret_cast<const float4*>(bta + lane * 8);
  const float4 b1 = *reinterpret_cast<const float4*>(bta + lane * 8 + 4);
  float y[8];
  y[0] = (v0.x - mean) * inv * g0.x + b0.x;
  y[1] = (v0.y - mean) * inv * g0.y + b0.y;
  y[2] = (v0.z - mean) * inv * g0.z + b0.z;
  y[3] = (v0.w - mean) * inv * g0.w + b0.w;
  y[4] = (v1.x - mean) * inv * g1.x + b1.x;
  y[5] = (v1.y - mean) * inv * g1.y + b1.y;
  y[6] = (v1.z - mean) * inv * g1.z + b1.z;
  y[7] = (v1.w - mean) * inv * g1.w + b1.w;
  if (OUTBF) {
    u16 tmp[8];
#pragma unroll
    for (int e = 0; e < 8; ++e) tmp[e] = f2bf(y[e]);
    *reinterpret_cast<uint4*>((u16*)out + (long)row * 512 + lane * 8) =
        *reinterpret_cast<const uint4*>(tmp);
  } else {
    float* o = (float*)out + (long)row * 512 + lane * 8;
    *reinterpret_cast<float4*>(o) = make_float4(y[0], y[1], y[2], y[3]);
    *reinterpret_cast<float4*>(o + 4) = make_float4(y[4], y[5], y[6], y[7]);
  }
}

// ------------------------------------------------------------------

extern "C" void kernel_launch(void* const* d_in, const int* in_sizes, int n_in,
                              void* d_out, int out_size, void* d_ws, size_t ws_size,
                              hipStream_t stream) {
  const float* in_x = (const float*)d_in[0];
  const float* ln1_g = (const float*)d_in[1];
  const float* ln1_b = (const float*)d_in[2];
  const float* Wqkv = (const float*)d_in[3];
  const float* bqkv = (const float*)d_in[4];
  const float* fsmn_w = (const float*)d_in[5];
  const float* Wout = (const float*)d_in[6];
  const float* bout = (const float*)d_in[7];
  const float* ln2_g = (const float*)d_in[8];
  const float* ln2_b = (const float*)d_in[9];
  const float* W1 = (const float*)d_in[10];
  const float* b1 = (const float*)d_in[11];
  const float* W2 = (const float*)d_in[12];
  const float* b2 = (const float*)d_in[13];
  const float* after_g = (const float*)d_in[14];
  const float* after_b = (const float*)d_in[15];

  const int T = 2048, D = 512, F = 2048, L = 8;

  char* p = (char*)d_ws;
  auto alloc = [&](size_t bytes) {
    char* r = p;
    p += (bytes + 255) & ~size_t(255);
    return r;
  };
  u16* WqkvT = (u16*)alloc(8L * 1536 * 512 * 2);
  u16* WoutT = (u16*)alloc(8L * 512 * 512 * 2);
  u16* W1T = (u16*)alloc(8L * 2048 * 512 * 2);
  u16* W2T = (u16*)alloc(8L * 512 * 2048 * 2);
  float* x = (float*)alloc((long)T * D * 4);
  u16* x1 = (u16*)alloc((long)T * D * 2);
  u16* qkv = (u16*)alloc((long)T * 1536 * 2);
  u16* vT = (u16*)alloc((long)D * T * 2);
  u16* attn = (u16*)alloc((long)T * D * 2);
  u16* hb = (u16*)alloc((long)T * F * 2);
  u16* oPart = (u16*)alloc(4L * T * D * 2);
  float* lPart = (float*)alloc(4L * 8 * T * 4);
  float* wPart = (float*)alloc(2L * T * D * 4);

  // ---- pre-pass: residual stream + bf16 transposed weights (1 dispatch) ----
  hipMemcpyAsync(x, in_x, (long)T * D * 4, hipMemcpyDeviceToDevice, stream);
  transpose_all<<<dim3(384 * 8, 1, 1), 256, 0, stream>>>(
      Wqkv, WqkvT, Wout, WoutT, W1, W1T, W2, W2T);

  const long OFB = (long)2048 * 512;
  for (int l = 0; l < L; ++l) {
    if (l == 0)
      ln_accum<1, 0><<<T / 4, 256, 0, stream>>>(x, (const float*)nullptr,
                                                ln1_g + 512 * l, ln1_b + 512 * l, x1);
    else
      ln_accum<1, 2><<<T / 4, 256, 0, stream>>>(x, wPart,
                                                ln1_g + 512 * l, ln1_b + 512 * l, x1);
    // QKV GEMM + fused vT emit
    gemm_bt<2, 2, 1><<<dim3(24, 32, 1), 256, 0, stream>>>(
        x1, 512, WqkvT + (long)l * 1536 * 512, 512, bqkv + 1536 * l,
        qkv, 1536, (float*)nullptr, 0, 0, vT, T, 1536, 512, 1, 1.f, 0);
    // flash attention partials
    flash_attn_split<<<dim3(512, 1, 1), 512, 0, stream>>>(qkv, vT, oPart, lPart);
    // combine partials -> attn, and x += fsmn(v)
    attn_norm_fsmn<<<T, 256, 0, stream>>>(oPart, lPart, attn, x, qkv,
                                          fsmn_w + (long)l * 512 * 11);
    // wPart[z] = attn @ Wout chunk z (+ bout in z=0)
    gemm_bt<2, 2, 0><<<dim3(8, 32, 2), 256, 0, stream>>>(
        attn, 512, WoutT + (long)l * 512 * 512, 512, bout + 512 * l,
        (u16*)nullptr, 0, wPart, 512, OFB, (u16*)nullptr, T, 512, 512, 2, 1.f, 0);
    // LN2 folds Wout partials
    ln_accum<1, 2><<<T / 4, 256, 0, stream>>>(x, wPart,
                                              ln2_g + 512 * l, ln2_b + 512 * l, x1);
    // hb = relu(x1 @ W1 + b1)
    gemm_bt<2, 2, 0><<<dim3(32, 32, 1), 256, 0, stream>>>(
        x1, 512, W1T + (long)l * 2048 * 512, 512, b1 + 2048 * l,
        hb, 2048, (float*)nullptr, 0, 0, (u16*)nullptr, T, 2048, 512, 1, 1.f, 1);
    // wPart[z] = hb @ W2 chunk z (+ b2 in z=0)
    gemm_bt<2, 2, 0><<<dim3(8, 32, 2), 256, 0, stream>>>(
        hb, 2048, W2T + (long)l * 512 * 2048, 2048, b2 + 512 * l,
        (u16*)nullptr, 0, wPart, 512, OFB, (u16*)nullptr, T, 512, 2048, 2, 1.f, 0);
  }
  // final LN folds layer 7's W2 partials
  ln_accum<0, 2><<<T / 4, 256, 0, stream>>>(x, wPart, after_g, after_b,
                                            (float*)d_out);
}